// Round 1
// baseline (747.783 us; speedup 1.0000x reference)
//
#include <hip/hip_runtime.h>

// DualMem fast_get_image_pred, restructured:
//   logits[b,c] = 100 * (Σ_m w_m sim_m) / sqrt(Σ_{i,j} w_i w_j G[c,i,j])
//   sim[b,c,m] = <img[b], mem[c,m]>,  w = exp(-beta(1-sim)),  G[c] = mem[c] mem[c]^T
// Avoids materializing adapt[b,c,d] (262 MB) entirely; mem is read from HBM once.

constexpr int Bn = 64;     // batch
constexpr int Cn = 1000;   // classes
constexpr int Mn = 11;     // memories per class
constexpr int Dn = 1024;   // feature dim
constexpr int NP = 66;     // Mn*(Mn+1)/2 unique Gram pairs
constexpr float BETA = 5.5f;

constexpr int CK = 128;        // K-chunk staged in LDS
constexpr int ISTR = CK + 1;   // padded LDS row stride (bank-conflict-free reads)

// p-th pair (i<=j) of the upper-triangular 11x11 Gram
constexpr int pairI(int p) {
    int i = 0;
    while (p >= Mn - i) { p -= Mn - i; ++i; }
    return i;
}
constexpr int pairJ(int p) {
    int i = 0;
    while (p >= Mn - i) { p -= Mn - i; ++i; }
    return i + p;
}

__global__ __launch_bounds__(256, 4) void dualmem_kernel(
    const float* __restrict__ img, const float* __restrict__ mem,
    float* __restrict__ out) {
    // LDS: staging (imgL 64x129 | memL 11x129) = 9675 floats = 38.7 KB
    // reused after compute for reduction buffers (redS 4x16x44 | red2 4x33)
    __shared__ float lds[(Bn + Mn) * ISTR];
    float* imgL = lds;
    float* memL = lds + Bn * ISTR;

    const int c    = blockIdx.x;
    const int tid  = threadIdx.x;
    const int lane = tid & 63;
    const int wid  = tid >> 6;
    const int bg   = tid & 15;   // b-group: owns b = 4*bg .. 4*bg+3
    const int ds   = tid >> 4;   // d-slice 0..15
    const int dd   = tid & 127;  // gram d within chunk
    const int half = tid >> 7;   // gram pair-half (wave-uniform)

    const float* memc = mem + (size_t)c * Mn * Dn;

    float acc[4][Mn];            // sim accumulators: 4 b's x 11 m
#pragma unroll
    for (int i = 0; i < 4; ++i)
#pragma unroll
        for (int m = 0; m < Mn; ++m) acc[i][m] = 0.f;
    float gacc[33];              // this thread's half of the 66 Gram pairs
#pragma unroll
    for (int q = 0; q < 33; ++q) gacc[q] = 0.f;

    for (int kc = 0; kc < Dn / CK; ++kc) {
        __syncthreads();  // previous chunk's LDS reads done before overwrite
        // stage img chunk (64x128) — coalesced float4 global loads
        for (int f = tid; f < Bn * CK / 4; f += 256) {
            int row = f >> 5;
            int c4  = f & 31;
            const float4 v =
                *reinterpret_cast<const float4*>(img + row * Dn + kc * CK + c4 * 4);
            float* p = imgL + row * ISTR + c4 * 4;
            p[0] = v.x; p[1] = v.y; p[2] = v.z; p[3] = v.w;
        }
        // stage mem chunk (11x128)
        for (int f = tid; f < Mn * CK; f += 256) {
            int row = f >> 7;
            int col = f & 127;
            memL[row * ISTR + col] = memc[row * Dn + kc * CK + col];
        }
        __syncthreads();
        // sim: d = ds + 16k keeps imgL at 2-way bank aliasing (free),
        // memL reads are 16-lane broadcasts
#pragma unroll
        for (int k = 0; k < CK / 16; ++k) {
            int d = ds + 16 * k;
            float x0 = imgL[(bg * 4 + 0) * ISTR + d];
            float x1 = imgL[(bg * 4 + 1) * ISTR + d];
            float x2 = imgL[(bg * 4 + 2) * ISTR + d];
            float x3 = imgL[(bg * 4 + 3) * ISTR + d];
#pragma unroll
            for (int m = 0; m < Mn; ++m) {
                float y = memL[m * ISTR + d];
                acc[0][m] = fmaf(x0, y, acc[0][m]);
                acc[1][m] = fmaf(x1, y, acc[1][m]);
                acc[2][m] = fmaf(x2, y, acc[2][m]);
                acc[3][m] = fmaf(x3, y, acc[3][m]);
            }
        }
        // gram: each thread covers one d (2x coverage over 256 threads),
        // wave-uniform half split of the 66 pairs
        {
            float v[Mn];
#pragma unroll
            for (int m = 0; m < Mn; ++m) v[m] = memL[m * ISTR + dd];
            if (half == 0) {
#pragma unroll
                for (int q = 0; q < 33; ++q)
                    gacc[q] = fmaf(v[pairI(q)], v[pairJ(q)], gacc[q]);
            } else {
#pragma unroll
                for (int q = 0; q < 33; ++q)
                    gacc[q] = fmaf(v[pairI(q + 33)], v[pairJ(q + 33)], gacc[q]);
            }
        }
    }

    // sim reduce across the 4 d-slices resident in each wave (lanes l, l+16, l+32, l+48)
#pragma unroll
    for (int i = 0; i < 4; ++i)
#pragma unroll
        for (int m = 0; m < Mn; ++m) {
            float x = acc[i][m];
            x += __shfl_down(x, 16, 64);
            x += __shfl_down(x, 32, 64);
            acc[i][m] = x;
        }
    // gram butterfly reduce across all 64 lanes of each wave
#pragma unroll
    for (int q = 0; q < 33; ++q) {
        float x = gacc[q];
#pragma unroll
        for (int off = 1; off < 64; off <<= 1) x += __shfl_xor(x, off, 64);
        gacc[q] = x;
    }

    __syncthreads();  // all LDS staging reads complete — safe to reuse for reductions
    float* redS = lds;         // [4 waves][16 bg][44]
    float* red2 = lds + 2816;  // [4 waves][33]
    if (lane < 16) {
#pragma unroll
        for (int i = 0; i < 4; ++i)
#pragma unroll
            for (int m = 0; m < Mn; ++m)
                redS[wid * 704 + lane * 44 + i * Mn + m] = acc[i][m];
    }
    if (lane == 0) {
#pragma unroll
        for (int q = 0; q < 33; ++q) red2[wid * 33 + q] = gacc[q];
    }
    __syncthreads();

    // finish: 64 threads, one per b
    if (tid < Bn) {
        const int b   = tid;
        const int bgo = b >> 2;
        const int io  = b & 3;
        float w[Mn];
        float numer = 0.f;
#pragma unroll
        for (int m = 0; m < Mn; ++m) {
            float s = redS[0 * 704 + bgo * 44 + io * Mn + m]
                    + redS[1 * 704 + bgo * 44 + io * Mn + m]
                    + redS[2 * 704 + bgo * 44 + io * Mn + m]
                    + redS[3 * 704 + bgo * 44 + io * Mn + m];
            w[m]  = __expf(BETA * (s - 1.f));
            numer = fmaf(w[m], s, numer);
        }
        float den2 = 0.f;
#pragma unroll
        for (int p = 0; p < NP; ++p) {
            // waves 0+1 reduced pairs 0..32, waves 2+3 reduced pairs 33..65
            float Gv = (p < 33) ? (red2[p] + red2[33 + p])
                                : (red2[66 + (p - 33)] + red2[99 + (p - 33)]);
            float term = w[pairI(p)] * w[pairJ(p)] * Gv;
            den2 += (pairI(p) == pairJ(p)) ? term : (2.f * term);
        }
        out[b * Cn + c] = 100.f * numer / sqrtf(den2);
    }
}

extern "C" void kernel_launch(void* const* d_in, const int* in_sizes, int n_in,
                              void* d_out, int out_size, void* d_ws, size_t ws_size,
                              hipStream_t stream) {
    const float* img = (const float*)d_in[0];  // [64][1024] f32
    const float* mem = (const float*)d_in[1];  // [1000][11][1024] f32
    float* out = (float*)d_out;                // [64][1000] f32
    (void)in_sizes; (void)n_in; (void)out_size; (void)d_ws; (void)ws_size;
    dualmem_kernel<<<dim3(Cn), dim3(256), 0, stream>>>(img, mem, out);
}

// Round 2
// 458.884 us; speedup vs baseline: 1.6296x; 1.6296x over previous
//
#include <hip/hip_runtime.h>

// DualMem fast_get_image_pred, restructured:
//   logits[b,c] = 100 * (Σ_m w_m sim_m) / sqrt(Σ_{i,j} w_i w_j G[c,i,j])
//   sim[b,c,m] = <img[b], mem[c,m]>,  w = exp(-beta(1-sim)),  G[c] = mem[c] mem[c]^T
// Avoids materializing adapt[b,c,d] (262 MB) entirely; mem is read from HBM once.
//
// R1 lesson: __launch_bounds__(256,4) capped VGPRs at 64 -> 77 persistent
// accumulators spilled to scratch (1.5 GB writes, 748 us). Use plain
// __launch_bounds__(256): ~100 live regs fit at 4 waves/SIMD, and grid=1000
// is ~4 blocks/CU anyway, so higher occupancy buys nothing.

constexpr int Bn = 64;     // batch
constexpr int Cn = 1000;   // classes
constexpr int Mn = 11;     // memories per class
constexpr int Dn = 1024;   // feature dim
constexpr int NP = 66;     // Mn*(Mn+1)/2 unique Gram pairs
constexpr float BETA = 5.5f;

constexpr int CK = 128;        // K-chunk staged in LDS
constexpr int ISTR = CK + 1;   // padded LDS row stride (bank-conflict-free reads)

// p-th pair (i<=j) of the upper-triangular 11x11 Gram
constexpr int pairI(int p) {
    int i = 0;
    while (p >= Mn - i) { p -= Mn - i; ++i; }
    return i;
}
constexpr int pairJ(int p) {
    int i = 0;
    while (p >= Mn - i) { p -= Mn - i; ++i; }
    return i + p;
}

__global__ __launch_bounds__(256) void dualmem_kernel(
    const float* __restrict__ img, const float* __restrict__ mem,
    float* __restrict__ out) {
    // LDS: staging (imgL 64x129 | memL 11x129) = 9675 floats = 38.7 KB
    // reused after compute for reduction buffers (redS 4x16x44 | red2 4x33)
    __shared__ float lds[(Bn + Mn) * ISTR];
    float* imgL = lds;
    float* memL = lds + Bn * ISTR;

    const int c    = blockIdx.x;
    const int tid  = threadIdx.x;
    const int lane = tid & 63;
    const int wid  = tid >> 6;
    const int bg   = tid & 15;   // b-group: owns b = 4*bg .. 4*bg+3
    const int ds   = tid >> 4;   // d-slice 0..15
    const int dd   = tid & 127;  // gram d within chunk
    const int half = tid >> 7;   // gram pair-half (wave-uniform)

    const float* memc = mem + (size_t)c * Mn * Dn;

    float acc[4][Mn];            // sim accumulators: 4 b's x 11 m
#pragma unroll
    for (int i = 0; i < 4; ++i)
#pragma unroll
        for (int m = 0; m < Mn; ++m) acc[i][m] = 0.f;
    float gacc[33];              // this thread's half of the 66 Gram pairs
#pragma unroll
    for (int q = 0; q < 33; ++q) gacc[q] = 0.f;

    for (int kc = 0; kc < Dn / CK; ++kc) {
        __syncthreads();  // previous chunk's LDS reads done before overwrite
        // stage img chunk (64x128) — coalesced float4 global loads
        for (int f = tid; f < Bn * CK / 4; f += 256) {
            int row = f >> 5;
            int c4  = f & 31;
            const float4 v =
                *reinterpret_cast<const float4*>(img + row * Dn + kc * CK + c4 * 4);
            float* p = imgL + row * ISTR + c4 * 4;
            p[0] = v.x; p[1] = v.y; p[2] = v.z; p[3] = v.w;
        }
        // stage mem chunk (11x128)
        for (int f = tid; f < Mn * CK; f += 256) {
            int row = f >> 7;
            int col = f & 127;
            memL[row * ISTR + col] = memc[row * Dn + kc * CK + col];
        }
        __syncthreads();
        // sim: d = ds + 16k keeps imgL at 2-way bank aliasing (free),
        // memL reads are 16-lane broadcasts
#pragma unroll
        for (int k = 0; k < CK / 16; ++k) {
            int d = ds + 16 * k;
            float x0 = imgL[(bg * 4 + 0) * ISTR + d];
            float x1 = imgL[(bg * 4 + 1) * ISTR + d];
            float x2 = imgL[(bg * 4 + 2) * ISTR + d];
            float x3 = imgL[(bg * 4 + 3) * ISTR + d];
#pragma unroll
            for (int m = 0; m < Mn; ++m) {
                float y = memL[m * ISTR + d];
                acc[0][m] = fmaf(x0, y, acc[0][m]);
                acc[1][m] = fmaf(x1, y, acc[1][m]);
                acc[2][m] = fmaf(x2, y, acc[2][m]);
                acc[3][m] = fmaf(x3, y, acc[3][m]);
            }
        }
        // gram: each thread covers one d (2x coverage over 256 threads),
        // wave-uniform half split of the 66 pairs
        {
            float v[Mn];
#pragma unroll
            for (int m = 0; m < Mn; ++m) v[m] = memL[m * ISTR + dd];
            if (half == 0) {
#pragma unroll
                for (int q = 0; q < 33; ++q)
                    gacc[q] = fmaf(v[pairI(q)], v[pairJ(q)], gacc[q]);
            } else {
#pragma unroll
                for (int q = 0; q < 33; ++q)
                    gacc[q] = fmaf(v[pairI(q + 33)], v[pairJ(q + 33)], gacc[q]);
            }
        }
    }

    // sim reduce across the 4 d-slices resident in each wave (lanes l, l+16, l+32, l+48)
#pragma unroll
    for (int i = 0; i < 4; ++i)
#pragma unroll
        for (int m = 0; m < Mn; ++m) {
            float x = acc[i][m];
            x += __shfl_down(x, 16, 64);
            x += __shfl_down(x, 32, 64);
            acc[i][m] = x;
        }
    // gram butterfly reduce across all 64 lanes of each wave
#pragma unroll
    for (int q = 0; q < 33; ++q) {
        float x = gacc[q];
#pragma unroll
        for (int off = 1; off < 64; off <<= 1) x += __shfl_xor(x, off, 64);
        gacc[q] = x;
    }

    __syncthreads();  // all LDS staging reads complete — safe to reuse for reductions
    float* redS = lds;         // [4 waves][16 bg][44]
    float* red2 = lds + 2816;  // [4 waves][33]
    if (lane < 16) {
#pragma unroll
        for (int i = 0; i < 4; ++i)
#pragma unroll
            for (int m = 0; m < Mn; ++m)
                redS[wid * 704 + lane * 44 + i * Mn + m] = acc[i][m];
    }
    if (lane == 0) {
#pragma unroll
        for (int q = 0; q < 33; ++q) red2[wid * 33 + q] = gacc[q];
    }
    __syncthreads();

    // finish: 64 threads, one per b
    if (tid < Bn) {
        const int b   = tid;
        const int bgo = b >> 2;
        const int io  = b & 3;
        float w[Mn];
        float numer = 0.f;
#pragma unroll
        for (int m = 0; m < Mn; ++m) {
            float s = redS[0 * 704 + bgo * 44 + io * Mn + m]
                    + redS[1 * 704 + bgo * 44 + io * Mn + m]
                    + redS[2 * 704 + bgo * 44 + io * Mn + m]
                    + redS[3 * 704 + bgo * 44 + io * Mn + m];
            w[m]  = __expf(BETA * (s - 1.f));
            numer = fmaf(w[m], s, numer);
        }
        float den2 = 0.f;
#pragma unroll
        for (int p = 0; p < NP; ++p) {
            // waves 0+1 reduced pairs 0..32, waves 2+3 reduced pairs 33..65
            float Gv = (p < 33) ? (red2[p] + red2[33 + p])
                                : (red2[66 + (p - 33)] + red2[99 + (p - 33)]);
            float term = w[pairI(p)] * w[pairJ(p)] * Gv;
            den2 += (pairI(p) == pairJ(p)) ? term : (2.f * term);
        }
        out[b * Cn + c] = 100.f * numer / sqrtf(den2);
    }
}

extern "C" void kernel_launch(void* const* d_in, const int* in_sizes, int n_in,
                              void* d_out, int out_size, void* d_ws, size_t ws_size,
                              hipStream_t stream) {
    const float* img = (const float*)d_in[0];  // [64][1024] f32
    const float* mem = (const float*)d_in[1];  // [1000][11][1024] f32
    float* out = (float*)d_out;                // [64][1000] f32
    (void)in_sizes; (void)n_in; (void)out_size; (void)d_ws; (void)ws_size;
    dualmem_kernel<<<dim3(Cn), dim3(256), 0, stream>>>(img, mem, out);
}

// Round 3
// 437.332 us; speedup vs baseline: 1.7099x; 1.0493x over previous
//
#include <hip/hip_runtime.h>

// DualMem fast_get_image_pred, restructured:
//   logits[b,c] = 100 * (Σ_m w_m sim_m) / sqrt(Σ_{i,j} w_i w_j G[c,i,j])
//   sim[b,c,m] = <img[b], mem[c,m]>,  w = exp(-beta(1-sim)),  G[c] = mem[c] mem[c]^T
//
// R2 lesson: the LDS-staged 8-chunk lockstep version ran 480us with ALL pipes
// <10% busy — stall-bound on 16 barriers/block + serial staging drains at ~1
// effective block/CU. This version: NO staging, NO mid-kernel barriers.
// Lane map ds=tid&15 makes per-thread d-slices {4*ds+64k} contiguous float4,
// so img and mem are read straight from global, perfectly coalesced (img is
// L2/L3-hot at 256KB; mem streams from HBM/L3 once). Each wave owns 4 b-rows
// over ALL d -> sim reduce is a 4-step in-wave shuffle. A 5th wave computes
// the 66-pair Gram with compile-time pair indices (no runtime-indexed regs).
// One __syncthreads total; LDS = 3KB.

constexpr int Bn = 64;     // batch
constexpr int Cn = 1000;   // classes
constexpr int Mn = 11;     // memories per class
constexpr int Dn = 1024;   // feature dim
constexpr int NP = 66;     // Mn*(Mn+1)/2 unique Gram pairs
constexpr float BETA = 5.5f;

// p-th pair (i<=j) of the upper-triangular 11x11 Gram
constexpr int pairI(int p) {
    int i = 0;
    while (p >= Mn - i) { p -= Mn - i; ++i; }
    return i;
}
constexpr int pairJ(int p) {
    int i = 0;
    while (p >= Mn - i) { p -= Mn - i; ++i; }
    return i + p;
}

__global__ __launch_bounds__(320) void dualmem_kernel(
    const float* __restrict__ img, const float* __restrict__ mem,
    float* __restrict__ out) {
    __shared__ float redS[16 * 44];  // [bg][4 local b][11 m] reduced sims
    __shared__ float redG[NP];       // reduced Gram pairs

    const int c   = blockIdx.x;
    const int tid = threadIdx.x;
    const float* __restrict__ memc = mem + (size_t)c * (Mn * Dn);

    if (tid < 256) {
        // ---- sim waves: thread (bg, ds) owns b = 4bg..4bg+3, d = 4ds+64k+{0..3}
        const int ds = tid & 15;
        const int bg = tid >> 4;
        float acc[4][Mn];
#pragma unroll
        for (int i = 0; i < 4; ++i)
#pragma unroll
            for (int m = 0; m < Mn; ++m) acc[i][m] = 0.f;

        const float* ip = img + (4 * bg) * Dn + 4 * ds;
        const float* mp = memc + 4 * ds;

        for (int k = 0; k < 16; ++k) {
            float4 iv[4];
            float4 mv[Mn];
#pragma unroll
            for (int i = 0; i < 4; ++i)
                iv[i] = *reinterpret_cast<const float4*>(ip + i * Dn + 64 * k);
#pragma unroll
            for (int m = 0; m < Mn; ++m)
                mv[m] = *reinterpret_cast<const float4*>(mp + m * Dn + 64 * k);
#pragma unroll
            for (int i = 0; i < 4; ++i)
#pragma unroll
                for (int m = 0; m < Mn; ++m) {
                    float a = acc[i][m];
                    a = fmaf(iv[i].x, mv[m].x, a);
                    a = fmaf(iv[i].y, mv[m].y, a);
                    a = fmaf(iv[i].z, mv[m].z, a);
                    a = fmaf(iv[i].w, mv[m].w, a);
                    acc[i][m] = a;
                }
        }
        // reduce over the 16 ds lanes (low 4 lane bits) — butterfly
#pragma unroll
        for (int i = 0; i < 4; ++i)
#pragma unroll
            for (int m = 0; m < Mn; ++m) {
                float x = acc[i][m];
                x += __shfl_xor(x, 1, 64);
                x += __shfl_xor(x, 2, 64);
                x += __shfl_xor(x, 4, 64);
                x += __shfl_xor(x, 8, 64);
                acc[i][m] = x;
            }
        if (ds == 0) {
#pragma unroll
            for (int i = 0; i < 4; ++i)
#pragma unroll
                for (int m = 0; m < Mn; ++m)
                    redS[bg * 44 + i * Mn + m] = acc[i][m];
        }
    } else {
        // ---- gram wave: lane l owns d = 4l+256k+{0..3}, all 66 pairs
        const int l = tid - 256;
        float g[NP];
#pragma unroll
        for (int p = 0; p < NP; ++p) g[p] = 0.f;
        const float* mp = memc + 4 * l;
        for (int k = 0; k < 4; ++k) {
            float4 v[Mn];
#pragma unroll
            for (int m = 0; m < Mn; ++m)
                v[m] = *reinterpret_cast<const float4*>(mp + m * Dn + 256 * k);
#pragma unroll
            for (int p = 0; p < NP; ++p) {
                const float4 a = v[pairI(p)];
                const float4 b = v[pairJ(p)];
                float x = g[p];
                x = fmaf(a.x, b.x, x);
                x = fmaf(a.y, b.y, x);
                x = fmaf(a.z, b.z, x);
                x = fmaf(a.w, b.w, x);
                g[p] = x;
            }
        }
#pragma unroll
        for (int p = 0; p < NP; ++p) {
            float x = g[p];
            x += __shfl_xor(x, 1, 64);
            x += __shfl_xor(x, 2, 64);
            x += __shfl_xor(x, 4, 64);
            x += __shfl_xor(x, 8, 64);
            x += __shfl_xor(x, 16, 64);
            x += __shfl_xor(x, 32, 64);
            g[p] = x;
        }
        if (l == 0) {
#pragma unroll
            for (int p = 0; p < NP; ++p) redG[p] = g[p];
        }
    }

    __syncthreads();  // the only barrier

    // ---- finish: one thread per b
    if (tid < Bn) {
        const int b = tid;
        float w[Mn];
        float numer = 0.f;
#pragma unroll
        for (int m = 0; m < Mn; ++m) {
            float s = redS[(b >> 2) * 44 + (b & 3) * Mn + m];
            w[m]  = __expf(BETA * (s - 1.f));
            numer = fmaf(w[m], s, numer);
        }
        float den2 = 0.f;
#pragma unroll
        for (int p = 0; p < NP; ++p) {
            float t = w[pairI(p)] * w[pairJ(p)] * redG[p];
            den2 += (pairI(p) == pairJ(p)) ? t : (2.f * t);
        }
        out[b * Cn + c] = 100.f * numer / sqrtf(den2);
    }
}

extern "C" void kernel_launch(void* const* d_in, const int* in_sizes, int n_in,
                              void* d_out, int out_size, void* d_ws, size_t ws_size,
                              hipStream_t stream) {
    const float* img = (const float*)d_in[0];  // [64][1024] f32
    const float* mem = (const float*)d_in[1];  // [1000][11][1024] f32
    float* out = (float*)d_out;                // [64][1000] f32
    (void)in_sizes; (void)n_in; (void)out_size; (void)d_ws; (void)ws_size;
    dualmem_kernel<<<dim3(Cn), dim3(320), 0, stream>>>(img, mem, out);
}

// Round 4
// 199.370 us; speedup vs baseline: 3.7507x; 2.1936x over previous
//
#include <hip/hip_runtime.h>

// DualMem fast_get_image_pred, restructured:
//   logits[b,c] = 100 * (Σ_m w_m sim_m) / sqrt(Σ_{i,j} w_i w_j G[c,i,j])
//   sim[b,c,m] = <img[b], mem[c,m]>,  w = exp(-beta(1-sim)),  G[c] = mem[c] mem[c]^T
//
// R2/R3 lesson: any thread role holding >~70 live fp32 values spills
// (VGPR cap ~128 at default heuristics), and spill round-trips inside the
// inner loop serialize the whole kernel (R3: 180 MB scratch writes, gram
// wave straggler behind __syncthreads, 470us at 5% VALUBusy).
// This version: THREE separate kernels (independent register allocation,
// zero mid-kernel barriers, no cross-role straggler), each role <=~75 live:
//   K1 sim:  thread owns 1 b x 11 m  -> acc[11] + 12 float4 transient
//   K2 gram: wave owns 16-17 pairs   -> g[17] + 11 float4 transient
//   K3 finish: thread owns one (b,c)
// ws layout: sim[1000][64][11] then gram[1000][66]  (3.1 MB total)

constexpr int Bn = 64;     // batch
constexpr int Cn = 1000;   // classes
constexpr int Mn = 11;     // memories per class
constexpr int Dn = 1024;   // feature dim
constexpr int NP = 66;     // Mn*(Mn+1)/2 unique Gram pairs
constexpr float BETA = 5.5f;

// p-th pair (i<=j) of the upper-triangular 11x11 Gram (compile-time p only!)
constexpr int pairI(int p) {
    int i = 0;
    while (p >= Mn - i) { p -= Mn - i; ++i; }
    return i;
}
constexpr int pairJ(int p) {
    int i = 0;
    while (p >= Mn - i) { p -= Mn - i; ++i; }
    return i + p;
}

// ---------------- K1: sim[c][b][m] ----------------
__global__ __launch_bounds__(256) void sim_kernel(
    const float* __restrict__ img, const float* __restrict__ mem,
    float* __restrict__ sim) {
    const int c  = blockIdx.x;
    const int b  = threadIdx.x >> 2;   // one b per thread
    const int ds = threadIdx.x & 3;    // d-slice: d = 4*ds + 16*k + {0..3}

    const float* ip = img + b * Dn + 4 * ds;
    const float* mp = mem + (size_t)c * (Mn * Dn) + 4 * ds;

    float acc[Mn];
#pragma unroll
    for (int m = 0; m < Mn; ++m) acc[m] = 0.f;

    for (int k = 0; k < Dn / 16; ++k) {   // 64 iterations
        const float4 iv = *reinterpret_cast<const float4*>(ip + 16 * k);
#pragma unroll
        for (int m = 0; m < Mn; ++m) {
            const float4 mv = *reinterpret_cast<const float4*>(mp + m * Dn + 16 * k);
            float a = acc[m];
            a = fmaf(iv.x, mv.x, a);
            a = fmaf(iv.y, mv.y, a);
            a = fmaf(iv.z, mv.z, a);
            a = fmaf(iv.w, mv.w, a);
            acc[m] = a;
        }
    }
    // reduce over the 4 ds lanes (low 2 lane bits)
#pragma unroll
    for (int m = 0; m < Mn; ++m) {
        float x = acc[m];
        x += __shfl_xor(x, 1, 64);
        x += __shfl_xor(x, 2, 64);
        acc[m] = x;
    }
    if (ds == 0) {
        float* o = sim + (size_t)c * (Bn * Mn) + b * Mn;
#pragma unroll
        for (int m = 0; m < Mn; ++m) o[m] = acc[m];
    }
}

// ---------------- K2: gram[c][p] ----------------
template <int P0, int P1>
__device__ inline void gramPairs(const float4* v, float* g) {
#pragma unroll
    for (int p = P0; p < P1; ++p) {           // p compile-time after unroll
        const float4 a = v[pairI(p)];
        const float4 b = v[pairJ(p)];
        float x = g[p - P0];
        x = fmaf(a.x, b.x, x);
        x = fmaf(a.y, b.y, x);
        x = fmaf(a.z, b.z, x);
        x = fmaf(a.w, b.w, x);
        g[p - P0] = x;
    }
}

__global__ __launch_bounds__(256) void gram_kernel(
    const float* __restrict__ mem, float* __restrict__ gram) {
    const int c = blockIdx.x;
    const int w = threadIdx.x >> 6;    // wave: pair group
    const int l = threadIdx.x & 63;    // lane: d = 4*l + 256*k + {0..3}

    const float* mp = mem + (size_t)c * (Mn * Dn) + 4 * l;

    float g[17];
#pragma unroll
    for (int q = 0; q < 17; ++q) g[q] = 0.f;

    for (int k = 0; k < 4; ++k) {
        float4 v[Mn];
#pragma unroll
        for (int m = 0; m < Mn; ++m)
            v[m] = *reinterpret_cast<const float4*>(mp + m * Dn + 256 * k);
        if (w == 0)      gramPairs<0, 17>(v, g);
        else if (w == 1) gramPairs<17, 34>(v, g);
        else if (w == 2) gramPairs<34, 50>(v, g);
        else             gramPairs<50, 66>(v, g);
    }
    // butterfly reduce each pair over the 64 lanes
#pragma unroll
    for (int q = 0; q < 17; ++q) {
        float x = g[q];
        x += __shfl_xor(x, 1, 64);
        x += __shfl_xor(x, 2, 64);
        x += __shfl_xor(x, 4, 64);
        x += __shfl_xor(x, 8, 64);
        x += __shfl_xor(x, 16, 64);
        x += __shfl_xor(x, 32, 64);
        g[q] = x;
    }
    const int np = (w < 2) ? 17 : 16;
    const int p0 = (w == 0) ? 0 : (w == 1) ? 17 : (w == 2) ? 34 : 50;
    if (l == 0) {
#pragma unroll
        for (int q = 0; q < 17; ++q)          // q compile-time, guard runtime
            if (q < np) gram[c * NP + p0 + q] = g[q];
    }
}

// ---------------- K3: logits ----------------
__global__ __launch_bounds__(256) void finish_kernel(
    const float* __restrict__ sim, const float* __restrict__ gram,
    float* __restrict__ out) {
    const int b = threadIdx.x & 63;
    const int c = blockIdx.x * 4 + (threadIdx.x >> 6);

    const float* sp = sim + (size_t)c * (Bn * Mn) + b * Mn;
    const float* gp = gram + c * NP;

    float w[Mn];
    float numer = 0.f;
#pragma unroll
    for (int m = 0; m < Mn; ++m) {
        const float s = sp[m];
        w[m]  = __expf(BETA * (s - 1.f));
        numer = fmaf(w[m], s, numer);
    }
    float den2 = 0.f;
#pragma unroll
    for (int p = 0; p < NP; ++p) {
        const float t = w[pairI(p)] * w[pairJ(p)] * gp[p];
        den2 += (pairI(p) == pairJ(p)) ? t : (2.f * t);
    }
    out[b * Cn + c] = 100.f * numer / sqrtf(den2);
}

extern "C" void kernel_launch(void* const* d_in, const int* in_sizes, int n_in,
                              void* d_out, int out_size, void* d_ws, size_t ws_size,
                              hipStream_t stream) {
    const float* img = (const float*)d_in[0];  // [64][1024] f32
    const float* mem = (const float*)d_in[1];  // [1000][11][1024] f32
    float* out = (float*)d_out;                // [64][1000] f32
    (void)in_sizes; (void)n_in; (void)out_size; (void)ws_size;

    float* ws_sim  = (float*)d_ws;             // [1000][64][11]
    float* ws_gram = ws_sim + Cn * Bn * Mn;    // [1000][66]

    sim_kernel<<<dim3(Cn), dim3(256), 0, stream>>>(img, mem, ws_sim);
    gram_kernel<<<dim3(Cn), dim3(256), 0, stream>>>(mem, ws_gram);
    finish_kernel<<<dim3(Cn / 4), dim3(256), 0, stream>>>(ws_sim, ws_gram, out);
}